// Round 15
// baseline (2047.231 us; speedup 1.0000x reference)
//
#include <hip/hip_runtime.h>
#include <hip/hip_bf16.h>
#include <hip/hip_fp16.h>
#include <cstddef>

// Problem constants: B=64, T=512, D=1024, H=1024
#define BATCH 64
#define TT    512
#define DD    1024
#define HH    1024

typedef _Float16 f16x8 __attribute__((ext_vector_type(8)));
typedef _Float16 f16x4 __attribute__((ext_vector_type(4)));
typedef float    f32x4 __attribute__((ext_vector_type(4)));
typedef unsigned long long u64;

union H8U2 { f16x8 v; u64 u[2]; };
union H4U1 { f16x4 h; u64 u; };
union F16P { _Float16 h[2]; unsigned u; };

#define MFMA16(a, b, c) __builtin_amdgcn_mfma_f32_16x16x32_f16((a), (b), (c), 0, 0, 0)

__device__ __forceinline__ float fast_tanh(float x) {
    float ax = __builtin_fabsf(x);
    float e  = __expf(-2.0f * ax);
    float r  = (1.0f - e) * __builtin_amdgcn_rcpf(1.0f + e);
    unsigned ur = (__float_as_uint(r) & 0x7fffffffu) | (__float_as_uint(x) & 0x80000000u);
    return __uint_as_float(ur);
}

__device__ __forceinline__ unsigned tagok(u64 lo, u64 hi, unsigned tagr) {
    unsigned ta = (unsigned)(lo & 1u) | (((unsigned)(lo >> 32) & 1u) << 1);
    unsigned tb = (unsigned)(hi & 1u) | (((unsigned)(hi >> 32) & 1u) << 1);
    return (unsigned)(ta == tagr) & (unsigned)(tb == tagr);
}

// ---- convert (GATHER): W [1024][1024] f32 -> A-fragment-order f16 ---------
__global__ __launch_bounds__(256) void convert_w(
    const float* __restrict__ W, _Float16* __restrict__ Wf,
    u64* __restrict__ hzero)
{
    if (hzero && blockIdx.x < 128)
        hzero[(size_t)blockIdx.x * 256 + threadIdx.x] = 0ull;

    int o2   = blockIdx.x * 256 + threadIdx.x;  // u32 index (2^19 total)
    int idx  = o2 * 2;                          // f16 element index
    int e    = idx & 7;                         // even
    int lane = (idx >> 3) & 63;
    int G    = idx >> 9;                        // cg*32 + kk
    int kk   = G & 31;
    int cg   = G >> 5;
    int c    = cg * 16 + (lane & 15);
    int k    = kk * 32 + ((lane >> 4) & 3) * 8 + e;

    float v0 = W[(size_t)k * 1024 + c];
    float v1 = W[(size_t)(k + 1) * 1024 + c];
    F16P p; p.h[0] = (_Float16)v0; p.h[1] = (_Float16)v1;
    ((unsigned*)Wf)[o2] = p.u;
}

// ---- Kernel A: xp = x @ Wx + bias, WxA LDS-staged per block (R14, keep) ---
__global__ __launch_bounds__(256, 1) void gemm_xp_mfma(
    const float* __restrict__ x,     // [32768][1024] f32
    const _Float16* __restrict__ WxA,// frag-ordered Wx^T
    const float* __restrict__ bias,  // [1024]
    float* __restrict__ out)         // [32768][1024] -> xp
{
    __shared__ char lds[2][32768];

    const int tid  = threadIdx.x;
    const int w    = tid >> 6;
    const int lane = tid & 63;
    const int l15  = lane & 15;
    const int lq   = lane >> 4;
    const int token0 = (blockIdx.x * 4 + w) * 16;

    f16x8 bfrag[32];
    {
        const float* xb = x + (size_t)(token0 + l15) * DD + lq * 8;
#pragma unroll
        for (int kk = 0; kk < 32; ++kk) {
            f32x4 lo = *(const f32x4*)(xb + kk * 32);
            f32x4 hi = *(const f32x4*)(xb + kk * 32 + 4);
            f16x8 f;
#pragma unroll
            for (int j = 0; j < 4; ++j) { f[j] = (_Float16)lo[j]; f[4 + j] = (_Float16)hi[j]; }
            bfrag[kk] = f;
        }
    }
#pragma unroll
    for (int kk = 0; kk < 32; ++kk) asm volatile("" : "+v"(bfrag[kk]));

    const size_t outb = (size_t)(token0 + l15) * HH + 4 * lq;

    {
        const int cg0 = blockIdx.x & 63;
        const f16x8* gp = (const f16x8*)WxA + (size_t)cg0 * 2048;
        f16x8 st[8];
#pragma unroll
        for (int j = 0; j < 8; ++j) st[j] = gp[tid + 256 * j];
#pragma unroll
        for (int j = 0; j < 8; ++j) *(f16x8*)(lds[0] + (tid + 256 * j) * 16) = st[j];
    }
    __syncthreads();

    for (int i = 0; i < 64; ++i) {
        const int cg = (i + blockIdx.x) & 63;

        f16x8 st[8];
        if (i + 1 < 64) {
            const int cgn = (i + 1 + blockIdx.x) & 63;
            const f16x8* gp = (const f16x8*)WxA + (size_t)cgn * 2048;
#pragma unroll
            for (int j = 0; j < 8; ++j) st[j] = gp[tid + 256 * j];
        }

        const char* lb = lds[i & 1];
        f32x4 acc0 = {0,0,0,0}, acc1 = {0,0,0,0}, acc2 = {0,0,0,0}, acc3 = {0,0,0,0};
#pragma unroll
        for (int q = 0; q < 8; ++q) {
            f16x8 a0 = *(const f16x8*)(lb + ((q*4 + 0) * 64 + lane) * 16);
            f16x8 a1 = *(const f16x8*)(lb + ((q*4 + 1) * 64 + lane) * 16);
            f16x8 a2 = *(const f16x8*)(lb + ((q*4 + 2) * 64 + lane) * 16);
            f16x8 a3 = *(const f16x8*)(lb + ((q*4 + 3) * 64 + lane) * 16);
            acc0 = MFMA16(a0, bfrag[q*4+0], acc0);
            acc1 = MFMA16(a1, bfrag[q*4+1], acc1);
            acc2 = MFMA16(a2, bfrag[q*4+2], acc2);
            acc3 = MFMA16(a3, bfrag[q*4+3], acc3);
        }
        f32x4 bv = *(const f32x4*)(bias + cg * 16 + 4 * lq);
        f32x4 r;
#pragma unroll
        for (int v = 0; v < 4; ++v)
            r[v] = ((acc0[v] + acc1[v]) + (acc2[v] + acc3[v])) + bv[v];
        *(f32x4*)(out + outb + cg * 16) = r;

        if (i + 1 < 64) {
            char* lw = lds[(i + 1) & 1];
#pragma unroll
            for (int j = 0; j < 8; ++j) *(f16x8*)(lw + (tid + 256 * j) * 16) = st[j];
        }
        __syncthreads();
    }
}

// ---- Kernel B: persistent scan, TWO bg-groups per block, phase-interleave -
// 32 blocks x 256 threads (4 waves). pair = bid&1 -> (bgA, bgB) = (2p, 2p+1);
// co4 = bid>>1, wave w owns cg = co4*4 + w for BOTH groups (same Wh frags).
// Per iteration t: [A check (vmcnt(3)) -> A stage -> barrier -> issue B polls
// -> A MFMA/tanh/tail(h,out,xp)] then the same for B (issuing A polls mid-B).
// Every poll is issued ~half an iteration AFTER the peer stores it samples
// (fresh snapshot) and its RTT hides under the other group's compute. The 3
// newest VMEM ops at any check are the other group's tail => constant
// vmcnt(3); this group's polls + xp are always drained for free.
// R6 tag protocol (mod-3 tags, sc0|sc1, self-healing retry) unchanged.
__global__ __launch_bounds__(256, 1) void rnn_persist(
    const _Float16* __restrict__ Whf,   // frag-ordered Wh^T
    _Float16* __restrict__ hb0,         // [64][1024] f16 (tagged)
    _Float16* __restrict__ hb1,         // [64][1024] f16 (tagged)
    float* __restrict__ out)            // [64][512][1024]; xp -> h in place
{
    __shared__ char ldsA[32768];        // group A h-tile (single buffer)
    __shared__ char ldsB[32768];        // group B h-tile

    const int tid  = threadIdx.x;
    const int pair = blockIdx.x & 1;        // bg pair {0,1} or {2,3}
    const int co4  = blockIdx.x >> 1;       // channel quad (4 cgs)
    const int w    = tid >> 6;
    const int cg   = co4 * 4 + w;           // 0..63 channel group
    const int lane = tid & 63;
    const int l15  = lane & 15;
    const int lq   = lane >> 4;
    const int bgA  = pair * 2;
    const int bgB  = pair * 2 + 1;

    // Resident A-frags (Wh^T): 32 x f16x8, pinned — shared by both groups.
    f16x8 afrag[32];
    {
        const f16x8* wp = (const f16x8*)Whf + (size_t)cg * 32 * 64 + lane;
#pragma unroll
        for (int kk = 0; kk < 32; ++kk) afrag[kk] = wp[(size_t)kk * 64];
    }
#pragma unroll
    for (int kk = 0; kk < 32; ++kk) asm volatile("" : "+v"(afrag[kk]));

    const int bA = bgA * 16 + l15;          // epilogue rows
    const int bB = bgB * 16 + l15;
    const int c  = cg * 16 + 4 * lq;        // first of this lane's 4 channels
    const size_t obA = (size_t)bA * TT * HH + c;
    const size_t obB = (size_t)bB * TT * HH + c;

    // Stage-phase constants: thread handles granules gi = tid + 256*i, i<8.
    unsigned soff[8];
    int rowA[8], rowB[8];                   // element offsets into hbuf
#pragma unroll
    for (int i = 0; i < 8; ++i) {
        int gi   = tid + 256 * i;
        int srow = gi >> 7;
        int scol = gi & 127;
        soff[i]  = ((unsigned)gi * 16u) ^ (unsigned)((srow & 7) << 4);
        rowA[i]  = (bgA * 16 + srow) * HH + scol * 8;
        rowB[i]  = (bgB * 16 + srow) * HH + scol * 8;
    }

    // Pre-loop: issue xp loads for t = 0 (xqA FIRST — older in the ledger).
    f32x4 xqA, xqB;
    {
        const float* pA = out + obA;
        asm volatile("global_load_dwordx4 %0, %1, off" : "=v"(xqA) : "v"(pA));
        const float* pB = out + obB;
        asm volatile("global_load_dwordx4 %0, %1, off" : "=v"(xqB) : "v"(pB));
    }

    H8U2 uu[8];                             // shared poll regs (never both live)

#define ISSUE_POLLS(rowarr, par)                                              \
    {                                                                         \
        const _Float16* _b = (par) ? hb1 : hb0;                               \
        _Pragma("unroll")                                                     \
        for (int _i = 0; _i < 8; ++_i) {                                      \
            const _Float16* _p = _b + rowarr[_i];                             \
            asm volatile("global_load_dwordx4 %0, %1, off sc0 sc1"            \
                         : "=v"(uu[_i].v) : "v"(_p));                         \
        }                                                                     \
    }

#define CHECK_RETRY(rowarr, par, tagr)                                        \
    while (true) {                                                            \
        unsigned _good = 1u;                                                  \
        _Pragma("unroll")                                                     \
        for (int _i = 0; _i < 8; ++_i)                                        \
            _good &= tagok(uu[_i].u[0], uu[_i].u[1], (tagr));                 \
        if (__all((int)_good)) break;                                         \
        __builtin_amdgcn_s_sleep(1);                                          \
        ISSUE_POLLS(rowarr, par);                                             \
        __builtin_amdgcn_sched_barrier(0);                                    \
        asm volatile("s_waitcnt vmcnt(0)" ::: "memory");                      \
        __builtin_amdgcn_sched_barrier(0);                                    \
    }

    for (int t = 0; t < TT; ++t) {
        const unsigned tagr = 1u + (unsigned)((t + 2) % 3);   // tag of h_{t-1}
        const unsigned tagw = 1u + (unsigned)(t % 3);
        const int tn = (t + 1 < TT) ? (t + 1) : t;            // clamped t+1

        // ================= PHASE A =================
        __builtin_amdgcn_sched_barrier(0);
        if (t > 0) { asm volatile("s_waitcnt vmcnt(3)" ::: "memory"); }
        else       { asm volatile("s_waitcnt vmcnt(1)" ::: "memory"); }
        __builtin_amdgcn_sched_barrier(0);

        if (t > 0) {
            CHECK_RETRY(rowA, (t + 1) & 1, tagr);             // h^A_{t-1}
#pragma unroll
            for (int i = 0; i < 8; ++i)
                *(f16x8*)(ldsA + soff[i]) = uu[i].v;
        }
        asm volatile("s_waitcnt lgkmcnt(0)\n\ts_barrier" ::: "memory");

        // mid-A: issue B's polls (h^B_{t-1} in hbuf[(t-1)&1])
        if (t > 0) ISSUE_POLLS(rowB, (t + 1) & 1);

        f32x4 acc0 = {0,0,0,0}, acc1 = {0,0,0,0}, acc2 = {0,0,0,0}, acc3 = {0,0,0,0};
        if (t > 0) {
            const unsigned rbase = (unsigned)(l15 * 2048);
            const unsigned rswz  = (unsigned)((l15 & 7) << 4);
#pragma unroll
            for (int q = 0; q < 8; ++q) {
                f16x8 b0 = *(const f16x8*)(ldsA + ((rbase + ((q*16 + 0*4 + lq) * 16u)) ^ rswz));
                f16x8 b1 = *(const f16x8*)(ldsA + ((rbase + ((q*16 + 1*4 + lq) * 16u)) ^ rswz));
                f16x8 b2 = *(const f16x8*)(ldsA + ((rbase + ((q*16 + 2*4 + lq) * 16u)) ^ rswz));
                f16x8 b3 = *(const f16x8*)(ldsA + ((rbase + ((q*16 + 3*4 + lq) * 16u)) ^ rswz));
                acc0 = MFMA16(afrag[q*4+0], b0, acc0);
                acc1 = MFMA16(afrag[q*4+1], b1, acc1);
                acc2 = MFMA16(afrag[q*4+2], b2, acc2);
                acc3 = MFMA16(afrag[q*4+3], b3, acc3);
            }
        }

        {   // epilogue A (xqA guaranteed by the check wait)
            f32x4 hvv; H4U1 pk;
#pragma unroll
            for (int v = 0; v < 4; ++v) {
                float s = ((acc0[v] + acc1[v]) + (acc2[v] + acc3[v])) + xqA[v];
                hvv[v] = fast_tanh(s);
                pk.h[v] = (_Float16)hvv[v];
            }
            pk.u = (pk.u & ~(1ull | (1ull << 32)))
                 | (u64)(tagw & 1u) | ((u64)(tagw >> 1) << 32);

            _Float16* q = ((t & 1) ? hb1 : hb0) + (size_t)bA * HH + c;
            asm volatile("global_store_dwordx2 %0, %1, off sc0 sc1"
                         :: "v"(q), "v"(pk.u) : "memory");
            const float* op = out + obA + (size_t)t * HH;
            asm volatile("global_store_dwordx4 %0, %1, off"
                         :: "v"(op), "v"(hvv) : "memory");
            const float* xpp = out + obA + (size_t)tn * HH;
            asm volatile("global_load_dwordx4 %0, %1, off" : "=v"(xqA) : "v"(xpp));
        }

        // ================= PHASE B =================
        __builtin_amdgcn_sched_barrier(0);
        asm volatile("s_waitcnt vmcnt(3)" ::: "memory");
        __builtin_amdgcn_sched_barrier(0);

        if (t > 0) {
            CHECK_RETRY(rowB, (t + 1) & 1, tagr);             // h^B_{t-1}
#pragma unroll
            for (int i = 0; i < 8; ++i)
                *(f16x8*)(ldsB + soff[i]) = uu[i].v;
        }
        asm volatile("s_waitcnt lgkmcnt(0)\n\ts_barrier" ::: "memory");

        // mid-B: issue A's polls for t+1 (h^A_t in hbuf[t&1])
        if (t + 1 < TT) ISSUE_POLLS(rowA, t & 1);

        acc0 = (f32x4){0,0,0,0}; acc1 = (f32x4){0,0,0,0};
        acc2 = (f32x4){0,0,0,0}; acc3 = (f32x4){0,0,0,0};
        if (t > 0) {
            const unsigned rbase = (unsigned)(l15 * 2048);
            const unsigned rswz  = (unsigned)((l15 & 7) << 4);
#pragma unroll
            for (int q = 0; q < 8; ++q) {
                f16x8 b0 = *(const f16x8*)(ldsB + ((rbase + ((q*16 + 0*4 + lq) * 16u)) ^ rswz));
                f16x8 b1 = *(const f16x8*)(ldsB + ((rbase + ((q*16 + 1*4 + lq) * 16u)) ^ rswz));
                f16x8 b2 = *(const f16x8*)(ldsB + ((rbase + ((q*16 + 2*4 + lq) * 16u)) ^ rswz));
                f16x8 b3 = *(const f16x8*)(ldsB + ((rbase + ((q*16 + 3*4 + lq) * 16u)) ^ rswz));
                acc0 = MFMA16(afrag[q*4+0], b0, acc0);
                acc1 = MFMA16(afrag[q*4+1], b1, acc1);
                acc2 = MFMA16(afrag[q*4+2], b2, acc2);
                acc3 = MFMA16(afrag[q*4+3], b3, acc3);
            }
        }

        {   // epilogue B
            f32x4 hvv; H4U1 pk;
#pragma unroll
            for (int v = 0; v < 4; ++v) {
                float s = ((acc0[v] + acc1[v]) + (acc2[v] + acc3[v])) + xqB[v];
                hvv[v] = fast_tanh(s);
                pk.h[v] = (_Float16)hvv[v];
            }
            pk.u = (pk.u & ~(1ull | (1ull << 32)))
                 | (u64)(tagw & 1u) | ((u64)(tagw >> 1) << 32);

            _Float16* q = ((t & 1) ? hb1 : hb0) + (size_t)bB * HH + c;
            asm volatile("global_store_dwordx2 %0, %1, off sc0 sc1"
                         :: "v"(q), "v"(pk.u) : "memory");
            const float* op = out + obB + (size_t)t * HH;
            asm volatile("global_store_dwordx4 %0, %1, off"
                         :: "v"(op), "v"(hvv) : "memory");
            const float* xpp = out + obB + (size_t)tn * HH;
            asm volatile("global_load_dwordx4 %0, %1, off" : "=v"(xqB) : "v"(xpp));
        }
    }
#undef ISSUE_POLLS
#undef CHECK_RETRY
}

extern "C" void kernel_launch(void* const* d_in, const int* in_sizes, int n_in,
                              void* d_out, int out_size, void* d_ws, size_t ws_size,
                              hipStream_t stream) {
    const float* x    = (const float*)d_in[0]; // [B, T, D]
    const float* Wx   = (const float*)d_in[1]; // [D, H]
    const float* Wh   = (const float*)d_in[2]; // [H, H]
    const float* bias = (const float*)d_in[3]; // [H]

    float* out = (float*)d_out;                // [B, T, H]

    // Workspace: Whf (2MB) | WxA (2MB) | hb0 (128KB) | hb1 (128KB)
    _Float16* Whf = (_Float16*)d_ws;
    _Float16* WxA = Whf + (1u << 20);
    _Float16* hb0 = WxA + (1u << 20);
    _Float16* hb1 = hb0 + BATCH * HH;

    // Weight conversions (gather form); Wh pass also zeroes hb0/hb1.
    convert_w<<<2048, 256, 0, stream>>>(Wh, Whf, (u64*)hb0);
    convert_w<<<2048, 256, 0, stream>>>(Wx, WxA, nullptr);

    // xp = x @ Wx + bias (f16 MFMA, LDS-staged WxA)
    gemm_xp_mfma<<<512, 256, 0, stream>>>(x, WxA, bias, out);

    // Persistent scan: 32 blocks x 256 threads, 2 bg-groups per block.
    rnn_persist<<<32, 256, 0, stream>>>(Whf, hb0, hb1, out);
}

// Round 16
// 1657.800 us; speedup vs baseline: 1.2349x; 1.2349x over previous
//
#include <hip/hip_runtime.h>
#include <hip/hip_bf16.h>
#include <hip/hip_fp16.h>
#include <cstddef>

// Problem constants: B=64, T=512, D=1024, H=1024
#define BATCH 64
#define TT    512
#define DD    1024
#define HH    1024

typedef _Float16 f16x8 __attribute__((ext_vector_type(8)));
typedef _Float16 f16x4 __attribute__((ext_vector_type(4)));
typedef float    f32x4 __attribute__((ext_vector_type(4)));
typedef unsigned long long u64;

union H8U2 { f16x8 v; u64 u[2]; };
union H4U1 { f16x4 h; u64 u; };
union F16P { _Float16 h[2]; unsigned u; };

#define MFMA16(a, b, c) __builtin_amdgcn_mfma_f32_16x16x32_f16((a), (b), (c), 0, 0, 0)

__device__ __forceinline__ float fast_tanh(float x) {
    float ax = __builtin_fabsf(x);
    float e  = __expf(-2.0f * ax);
    float r  = (1.0f - e) * __builtin_amdgcn_rcpf(1.0f + e);
    unsigned ur = (__float_as_uint(r) & 0x7fffffffu) | (__float_as_uint(x) & 0x80000000u);
    return __uint_as_float(ur);
}

__device__ __forceinline__ unsigned tagok(u64 lo, u64 hi, unsigned tagr) {
    unsigned ta = (unsigned)(lo & 1u) | (((unsigned)(lo >> 32) & 1u) << 1);
    unsigned tb = (unsigned)(hi & 1u) | (((unsigned)(hi >> 32) & 1u) << 1);
    return (unsigned)(ta == tagr) & (unsigned)(tb == tagr);
}

// ---- convert (GATHER): W [1024][1024] f32 -> A-fragment-order f16 ---------
// Thread owns one u32 (2 f16) of Wf, gathers the two f32 inputs. Coalesced
// 4B writes. Also zeroes the h double-buffer (tag reset for graph replay).
__global__ __launch_bounds__(256) void convert_w(
    const float* __restrict__ W, _Float16* __restrict__ Wf,
    u64* __restrict__ hzero)
{
    if (hzero && blockIdx.x < 128)
        hzero[(size_t)blockIdx.x * 256 + threadIdx.x] = 0ull;

    int o2   = blockIdx.x * 256 + threadIdx.x;  // u32 index (2^19 total)
    int idx  = o2 * 2;                          // f16 element index
    int e    = idx & 7;                         // even
    int lane = (idx >> 3) & 63;
    int G    = idx >> 9;                        // cg*32 + kk
    int kk   = G & 31;
    int cg   = G >> 5;
    int c    = cg * 16 + (lane & 15);
    int k    = kk * 32 + ((lane >> 4) & 3) * 8 + e;

    float v0 = W[(size_t)k * 1024 + c];
    float v1 = W[(size_t)(k + 1) * 1024 + c];
    F16P p; p.h[0] = (_Float16)v0; p.h[1] = (_Float16)v1;
    ((unsigned*)Wf)[o2] = p.u;
}

// ---- Kernel A: xp = x @ Wx + bias, WxA LDS-staged per block (R14, keep) ---
// 4 waves share one LDS copy of each cg's 32KB fragment block (L2 traffic /4).
// Double-buffered; stage loads for cg_{i+1} overlap MFMA on cg_i.
__global__ __launch_bounds__(256, 1) void gemm_xp_mfma(
    const float* __restrict__ x,     // [32768][1024] f32
    const _Float16* __restrict__ WxA,// frag-ordered Wx^T
    const float* __restrict__ bias,  // [1024]
    float* __restrict__ out)         // [32768][1024] -> xp
{
    __shared__ char lds[2][32768];

    const int tid  = threadIdx.x;
    const int w    = tid >> 6;
    const int lane = tid & 63;
    const int l15  = lane & 15;
    const int lq   = lane >> 4;
    const int token0 = (blockIdx.x * 4 + w) * 16;

    f16x8 bfrag[32];
    {
        const float* xb = x + (size_t)(token0 + l15) * DD + lq * 8;
#pragma unroll
        for (int kk = 0; kk < 32; ++kk) {
            f32x4 lo = *(const f32x4*)(xb + kk * 32);
            f32x4 hi = *(const f32x4*)(xb + kk * 32 + 4);
            f16x8 f;
#pragma unroll
            for (int j = 0; j < 4; ++j) { f[j] = (_Float16)lo[j]; f[4 + j] = (_Float16)hi[j]; }
            bfrag[kk] = f;
        }
    }
#pragma unroll
    for (int kk = 0; kk < 32; ++kk) asm volatile("" : "+v"(bfrag[kk]));

    const size_t outb = (size_t)(token0 + l15) * HH + 4 * lq;

    {
        const int cg0 = blockIdx.x & 63;
        const f16x8* gp = (const f16x8*)WxA + (size_t)cg0 * 2048;
        f16x8 st[8];
#pragma unroll
        for (int j = 0; j < 8; ++j) st[j] = gp[tid + 256 * j];
#pragma unroll
        for (int j = 0; j < 8; ++j) *(f16x8*)(lds[0] + (tid + 256 * j) * 16) = st[j];
    }
    __syncthreads();

    for (int i = 0; i < 64; ++i) {
        const int cg = (i + blockIdx.x) & 63;           // rotation spreads L2

        f16x8 st[8];
        if (i + 1 < 64) {
            const int cgn = (i + 1 + blockIdx.x) & 63;
            const f16x8* gp = (const f16x8*)WxA + (size_t)cgn * 2048;
#pragma unroll
            for (int j = 0; j < 8; ++j) st[j] = gp[tid + 256 * j];
        }

        const char* lb = lds[i & 1];
        f32x4 acc0 = {0,0,0,0}, acc1 = {0,0,0,0}, acc2 = {0,0,0,0}, acc3 = {0,0,0,0};
#pragma unroll
        for (int q = 0; q < 8; ++q) {
            f16x8 a0 = *(const f16x8*)(lb + ((q*4 + 0) * 64 + lane) * 16);
            f16x8 a1 = *(const f16x8*)(lb + ((q*4 + 1) * 64 + lane) * 16);
            f16x8 a2 = *(const f16x8*)(lb + ((q*4 + 2) * 64 + lane) * 16);
            f16x8 a3 = *(const f16x8*)(lb + ((q*4 + 3) * 64 + lane) * 16);
            acc0 = MFMA16(a0, bfrag[q*4+0], acc0);
            acc1 = MFMA16(a1, bfrag[q*4+1], acc1);
            acc2 = MFMA16(a2, bfrag[q*4+2], acc2);
            acc3 = MFMA16(a3, bfrag[q*4+3], acc3);
        }
        f32x4 bv = *(const f32x4*)(bias + cg * 16 + 4 * lq);
        f32x4 r;
#pragma unroll
        for (int v = 0; v < 4; ++v)
            r[v] = ((acc0[v] + acc1[v]) + (acc2[v] + acc3[v])) + bv[v];
        *(f32x4*)(out + outb + cg * 16) = r;

        if (i + 1 < 64) {
            char* lw = lds[(i + 1) & 1];
#pragma unroll
            for (int j = 0; j < 8; ++j) *(f16x8*)(lw + (tid + 256 * j) * 16) = st[j];
        }
        __syncthreads();
    }
}

// ---- Kernel B: persistent scan (R13 exact — best measured: 2.98 us/step) --
// 64 blocks x 256 threads (4 waves). Block = (bg = bid&3, co4 = bid>>2);
// wave w owns cg = co4*4 + w. R6 tag protocol (mod-3 tags in dword LSBs,
// sc0|sc1 via L3). Per-iteration asm VMEM order:
//   tail(t):  h-store -> polls x8 -> out-store -> xp-load(t+1)
//   check(t+1): vmcnt(2)  => h-store + all polls retired; out/xp may linger
//   epilogue(t): vmcnt(0) => xp(t) ready (everything it waits is ~1 step old)
// No plain VMEM inside the loop — the vmcnt ledger is fully asm-controlled.
// Own-block granules go straight into next step's LDS tile (no L3 self-race).
__global__ __launch_bounds__(256, 1) void rnn_persist(
    const _Float16* __restrict__ Whf,   // frag-ordered Wh^T
    _Float16* __restrict__ hb0,         // [64][1024] f16 (tagged)
    _Float16* __restrict__ hb1,         // [64][1024] f16 (tagged)
    float* __restrict__ out)            // [64][512][1024]; xp -> h in place
{
    __shared__ char ldsraw[65536];      // 2 x 32 KB h-tile double buffer

    const int tid  = threadIdx.x;
    const int bg   = blockIdx.x & 3;        // batch group (16 rows)
    const int co4  = blockIdx.x >> 2;       // channel quad (4 cgs)
    const int w    = tid >> 6;
    const int cg   = co4 * 4 + w;           // 0..63 channel group
    const int lane = tid & 63;
    const int l15  = lane & 15;
    const int lq   = lane >> 4;

    // Resident A-frags (Wh^T): 32 x f16x8, pinned (live across whole scan).
    f16x8 afrag[32];
    {
        const f16x8* wp = (const f16x8*)Whf + (size_t)cg * 32 * 64 + lane;
#pragma unroll
        for (int kk = 0; kk < 32; ++kk) afrag[kk] = wp[(size_t)kk * 64];
    }
#pragma unroll
    for (int kk = 0; kk < 32; ++kk) asm volatile("" : "+v"(afrag[kk]));

    _Float16* hbuf[2] = {hb0, hb1};

    const int b = bg * 16 + l15;            // this lane's batch row (epilogue)
    const int c = cg * 16 + 4 * lq;         // first of this lane's 4 channels
    const size_t ob = (size_t)b * TT * HH + c;

    // Stage-phase constants: thread handles granules gi = tid + 256*i, i<8.
    unsigned soff[8];                       // swizzled LDS byte offsets
    const _Float16* src0[8];                // source in hb0
    const _Float16* src1[8];                // source in hb1
    unsigned ownm = 0u;                     // granules owned by this block
#pragma unroll
    for (int i = 0; i < 8; ++i) {
        int gi   = tid + 256 * i;
        int srow = gi >> 7;                 // 0..15 within the bg tile
        int scol = gi & 127;                // 16B granule within row
        soff[i]  = ((unsigned)gi * 16u) ^ (unsigned)((srow & 7) << 4);
        src0[i]  = hb0 + (size_t)(bg * 16 + srow) * HH + scol * 8;
        src1[i]  = hb1 + (size_t)(bg * 16 + srow) * HH + scol * 8;
        if ((scol >> 3) == co4) ownm |= (1u << i);   // our block's channels
    }

    // Epilogue LDS write address (own 8B into next tile, swizzled).
    const unsigned g16 = (unsigned)(c >> 3);
    const unsigned eb  = (unsigned)(l15 * 2048)
                       + ((g16 * 16u) ^ (unsigned)((l15 & 7) << 4))
                       + 8u * (unsigned)(lq & 1);

    // Pre-loop: issue xp load for t = 0 (asm, loop-carried register).
    f32x4 xq;
    {
        const float* xpp = out + ob;
        asm volatile("global_load_dwordx4 %0, %1, off" : "=v"(xq) : "v"(xpp));
    }

    H8U2 uu[8];                             // in-flight poll loads

    for (int t = 0; t < TT; ++t) {
        // ---- [1] check: polls for h_{t-1} (issued in step t-1's tail) -----
        if (t > 0) {
            const unsigned tagr = 1u + (unsigned)((t - 1) % 3);
            const _Float16* const* src = ((t + 1) & 1) ? src1 : src0;

            __builtin_amdgcn_sched_barrier(0);
            asm volatile("s_waitcnt vmcnt(2)" ::: "memory");   // polls + h-store done
            __builtin_amdgcn_sched_barrier(0);

            while (true) {
                unsigned good = 1u;
#pragma unroll
                for (int i = 0; i < 8; ++i) {
                    unsigned ok = tagok(uu[i].u[0], uu[i].u[1], tagr);
                    good &= (ok | ((ownm >> i) & 1u));
                }
                if (__all((int)good)) break;
                __builtin_amdgcn_s_sleep(1);
#pragma unroll
                for (int i = 0; i < 8; ++i)
                    asm volatile("global_load_dwordx4 %0, %1, off sc0 sc1"
                                 : "=v"(uu[i].v) : "v"(src[i]));
                __builtin_amdgcn_sched_barrier(0);
                asm volatile("s_waitcnt vmcnt(0)" ::: "memory");
                __builtin_amdgcn_sched_barrier(0);
            }

            // stage verified peer granules into LDS (own ones already there)
            char* lb = ldsraw + (t & 1) * 32768;
#pragma unroll
            for (int i = 0; i < 8; ++i)
                if (!((ownm >> i) & 1u))
                    *(f16x8*)(lb + soff[i]) = uu[i].v;
        }

        // ---- [2] raw fused barrier: LDS drain + s_barrier, no vmcnt -------
        asm volatile("s_waitcnt lgkmcnt(0)\n\ts_barrier" ::: "memory");

        // ---- [3] compute: B-frags from LDS, MFMA vs pinned afrag ----------
        f32x4 acc0 = {0,0,0,0}, acc1 = {0,0,0,0}, acc2 = {0,0,0,0}, acc3 = {0,0,0,0};
        if (t > 0) {
            const char* lb = ldsraw + (t & 1) * 32768;
            const unsigned rbase = (unsigned)(l15 * 2048);
            const unsigned rswz  = (unsigned)((l15 & 7) << 4);
#pragma unroll
            for (int q = 0; q < 8; ++q) {
                f16x8 b0, b1, b2, b3;
                b0 = *(const f16x8*)(lb + ((rbase + ((q*16 + 0*4 + lq) * 16u)) ^ rswz));
                b1 = *(const f16x8*)(lb + ((rbase + ((q*16 + 1*4 + lq) * 16u)) ^ rswz));
                b2 = *(const f16x8*)(lb + ((rbase + ((q*16 + 2*4 + lq) * 16u)) ^ rswz));
                b3 = *(const f16x8*)(lb + ((rbase + ((q*16 + 3*4 + lq) * 16u)) ^ rswz));
                acc0 = MFMA16(afrag[q*4+0], b0, acc0);
                acc1 = MFMA16(afrag[q*4+1], b1, acc1);
                acc2 = MFMA16(afrag[q*4+2], b2, acc2);
                acc3 = MFMA16(afrag[q*4+3], b3, acc3);
            }
        }

        // ---- [4] epilogue: ensure xp(t) arrived, tanh, tag, own-LDS -------
        __builtin_amdgcn_sched_barrier(0);
        asm volatile("s_waitcnt vmcnt(0)" ::: "memory");   // xp(t) ready (old ops)
        __builtin_amdgcn_sched_barrier(0);

        const unsigned tagw = 1u + (unsigned)(t % 3);
        f32x4 hvv;
        H4U1 pk;
#pragma unroll
        for (int v = 0; v < 4; ++v) {
            float s = ((acc0[v] + acc1[v]) + (acc2[v] + acc3[v])) + xq[v];
            hvv[v] = fast_tanh(s);
            pk.h[v] = (_Float16)hvv[v];
        }
        pk.u = (pk.u & ~(1ull | (1ull << 32)))
             | (u64)(tagw & 1u) | ((u64)(tagw >> 1) << 32);

        // own granule straight into next step's LDS tile (no L3 round-trip)
        if (t + 1 < TT)
            *(u64*)(ldsraw + ((t + 1) & 1) * 32768 + eb) = pk.u;

        // ---- [5] tail, pinned asm order: h-store -> polls -> out -> xp ----
        {
            _Float16* q = hbuf[t & 1] + (size_t)b * HH + c;
            asm volatile("global_store_dwordx2 %0, %1, off sc0 sc1"
                         :: "v"(q), "v"(pk.u) : "memory");
        }
        if (t + 1 < TT) {
            const _Float16* const* src = (t & 1) ? src1 : src0;  // hbuf[t&1]
#pragma unroll
            for (int i = 0; i < 8; ++i)
                asm volatile("global_load_dwordx4 %0, %1, off sc0 sc1"
                             : "=v"(uu[i].v) : "v"(src[i]));
        }
        {
            const float* op = out + ob + (size_t)t * HH;
            asm volatile("global_store_dwordx4 %0, %1, off"
                         :: "v"(op), "v"(hvv) : "memory");
        }
        if (t + 1 < TT) {
            const float* xpp = out + ob + (size_t)(t + 1) * HH;
            asm volatile("global_load_dwordx4 %0, %1, off" : "=v"(xq) : "v"(xpp));
        }
    }
}

extern "C" void kernel_launch(void* const* d_in, const int* in_sizes, int n_in,
                              void* d_out, int out_size, void* d_ws, size_t ws_size,
                              hipStream_t stream) {
    const float* x    = (const float*)d_in[0]; // [B, T, D]
    const float* Wx   = (const float*)d_in[1]; // [D, H]
    const float* Wh   = (const float*)d_in[2]; // [H, H]
    const float* bias = (const float*)d_in[3]; // [H]

    float* out = (float*)d_out;                // [B, T, H]

    // Workspace: Whf (2MB) | WxA (2MB) | hb0 (128KB) | hb1 (128KB)
    _Float16* Whf = (_Float16*)d_ws;
    _Float16* WxA = Whf + (1u << 20);
    _Float16* hb0 = WxA + (1u << 20);
    _Float16* hb1 = hb0 + BATCH * HH;

    // Weight conversions (gather form); Wh pass also zeroes hb0/hb1.
    convert_w<<<2048, 256, 0, stream>>>(Wh, Whf, (u64*)hb0);
    convert_w<<<2048, 256, 0, stream>>>(Wx, WxA, nullptr);

    // xp = x @ Wx + bias (f16 MFMA, LDS-staged WxA)
    gemm_xp_mfma<<<512, 256, 0, stream>>>(x, WxA, bias, out);

    // Persistent scan: 64 blocks x 256 threads (4 waves), co-resident.
    rnn_persist<<<64, 256, 0, stream>>>(Whf, hb0, hb1, out);
}